// Round 9
// baseline (137.651 us; speedup 1.0000x reference)
//
#include <hip/hip_runtime.h>
#include <hip/hip_fp16.h>

typedef _Float16 f16;
typedef _Float16 half8 __attribute__((ext_vector_type(8)));
typedef float f32x4 __attribute__((ext_vector_type(4)));

#define BATCH 8
#define NTOK 2048
#define FIN 256
#define FOUT 256
#define ALPHA 0.2f
#define WHS 2080   // WhT row stride (pad breaks 4KB power-of-2 stride)

// ---------------- K0: W[k][o] fp32 -> WT[o][k] fp16 ----------------
__global__ void k_wt(const float* __restrict__ W, f16* __restrict__ WT) {
    __shared__ float t[32][33];
    int o0 = blockIdx.x * 32, k0 = blockIdx.y * 32;
    int tx = threadIdx.x, ty = threadIdx.y;
    t[ty][tx] = W[(k0 + ty) * FOUT + o0 + tx];
    __syncthreads();
    WT[(o0 + ty) * FIN + (k0 + tx)] = (f16)t[tx][ty];
}

// ---------------- K pack: adj int32 -> bitmask (dedicated streamer) ----------------
__global__ __launch_bounds__(256) void k_pack(const int* __restrict__ adj,
                                              unsigned long long* __restrict__ mask) {
    int lane = threadIdx.x & 63;
    size_t wv = (((size_t)blockIdx.x * 256 + threadIdx.x) >> 6);
    for (int it = 0; it < 8; it++) {
        size_t wave = wv + (size_t)it * 16384;
        const int* base = adj + wave * 256;
        unsigned long long m0 = __ballot(base[lane] > 0);
        unsigned long long m1 = __ballot(base[64 + lane] > 0);
        unsigned long long m2 = __ballot(base[128 + lane] > 0);
        unsigned long long m3 = __ballot(base[192 + lane] > 0);
        if (lane < 4) {
            unsigned long long v = lane == 0 ? m0 : lane == 1 ? m1 : lane == 2 ? m2 : m3;
            mask[wave * 4 + lane] = v;
        }
    }
}

// ---------------- K1: Wh = x @ W, store WhT[b][o][n] fp16 ----------------
__global__ __launch_bounds__(256) void k_gemm(const float* __restrict__ x,
                                              const f16* __restrict__ WT,
                                              f16* __restrict__ WhT) {
    __shared__ f16 Ah[64][72];
    __shared__ f16 Bt[256][72];
    int m0 = blockIdx.x * 64;
    int t = threadIdx.x;
    int lane = t & 63, w = t >> 6;
    f32x4 acc[4][4] = {};

    for (int k0 = 0; k0 < FIN; k0 += 64) {
        {
            int r = t >> 2, c = (t & 3) * 16;
            const float* src = x + (size_t)(m0 + r) * FIN + k0 + c;
            f16 tmp[16];
#pragma unroll
            for (int q = 0; q < 16; q++) tmp[q] = (f16)src[q];
            *(half8*)&Ah[r][c] = *(half8*)&tmp[0];
            *(half8*)&Ah[r][c + 8] = *(half8*)&tmp[8];
        }
        {
            const f16* src = WT + (size_t)t * FIN + k0;
#pragma unroll
            for (int q = 0; q < 8; q++)
                *(half8*)&Bt[t][q * 8] = *(const half8*)&src[q * 8];
        }
        __syncthreads();
#pragma unroll
        for (int kc = 0; kc < 2; kc++) {
            int krow = kc * 32 + ((lane >> 4) * 8);
            half8 af[4], bf[4];
#pragma unroll
            for (int fi = 0; fi < 4; fi++)
                af[fi] = *(half8*)&Ah[fi * 16 + (lane & 15)][krow];
#pragma unroll
            for (int fo = 0; fo < 4; fo++)
                bf[fo] = *(half8*)&Bt[w * 64 + fo * 16 + (lane & 15)][krow];
#pragma unroll
            for (int fi = 0; fi < 4; fi++)
#pragma unroll
                for (int fo = 0; fo < 4; fo++)
                    acc[fi][fo] = __builtin_amdgcn_mfma_f32_16x16x32_f16(
                        af[fi], bf[fo], acc[fi][fo], 0, 0, 0);
        }
        __syncthreads();
    }
    int b = m0 >> 11;
    int nbase = m0 & (NTOK - 1);
#pragma unroll
    for (int fi = 0; fi < 4; fi++)
#pragma unroll
        for (int fo = 0; fo < 4; fo++) {
            int o = w * 64 + fo * 16 + (lane & 15);
#pragma unroll
            for (int q = 0; q < 4; q++) {
                int n = nbase + fi * 16 + (lane >> 4) * 4 + q;
                WhT[((size_t)b * FOUT + o) * WHS + n] = (f16)acc[fi][fo][q];
            }
        }
}

// ---------------- K2: s1 = Wh@a1, s2 = Wh@a2 ----------------
__global__ __launch_bounds__(256) void k_s12(const f16* __restrict__ WhT,
                                             const float* __restrict__ a,
                                             float* __restrict__ s1,
                                             float* __restrict__ s2) {
    int b = blockIdx.y;
    int n = blockIdx.x * 256 + threadIdx.x;
    const f16* base = WhT + (size_t)b * FOUT * WHS + n;
    float a1 = 0.f, a2 = 0.f;
#pragma unroll 4
    for (int o = 0; o < FOUT; o++) {
        float wh = (float)base[(size_t)o * WHS];
        a1 += wh * a[o];
        a2 += wh * a[FOUT + o];
    }
    s1[b * NTOK + n] = a1;
    s2[b * NTOK + n] = a2;
}

// ---------------- K2b: mrow[b][i] = lrelu(s1[b][i] + max_j s2[b][j]) ----------------
__global__ __launch_bounds__(256) void k_rowmax(const float* __restrict__ s1,
                                                const float* __restrict__ s2,
                                                float* __restrict__ mrow) {
    __shared__ float red[4];
    int b = blockIdx.x, t = threadIdx.x;
    const float* s2b = s2 + (size_t)b * NTOK;
    float mx = -3.0e38f;
#pragma unroll
    for (int i = 0; i < 8; i++) mx = fmaxf(mx, s2b[t + i * 256]);
#pragma unroll
    for (int d = 1; d < 64; d <<= 1) mx = fmaxf(mx, __shfl_xor(mx, d));
    if ((t & 63) == 0) red[t >> 6] = mx;
    __syncthreads();
    float s2m = fmaxf(fmaxf(red[0], red[1]), fmaxf(red[2], red[3]));
#pragma unroll
    for (int i = 0; i < 8; i++) {
        int n = t + i * 256;
        float s = s1[(size_t)b * NTOK + n] + s2m;
        mrow[(size_t)b * NTOK + n] = fmaxf(s, ALPHA * s);
    }
}

// ---------------- K3: fused softmax(fixed shift) + P@Wh + ELU ----------------
// 64-row blocks, 8 waves: jq=w&1 (1024-j half), oh=(w>>1)&1 (128-o half),
// rg=w>>2 (32-row group). P in-register in MFMA A-layout; B-fragments
// explicitly DOUBLE-BUFFERED (bfA/bfB, issued one sub-iter ahead) so L2
// latency hides under softmax VALU. launch_bounds(512,2): VGPR cap 256.
// Grid = 256 blocks = exactly 1/CU, batch->XCD pinned. No main-loop barriers.

#define LOADB(DST, JT)                                              \
    {                                                               \
        const f16* wn_ = wb + (JT) * 32;                            \
        _Pragma("unroll")                                           \
        for (int ot_ = 0; ot_ < 8; ot_++)                           \
            DST[ot_] = *(const half8*)(wn_ + ot_ * 16 * WHS);       \
    }

#define SUBITER(JT, BFC)                                            \
    {                                                               \
        int sh2_ = (((JT) & 1) << 5) + (lg << 3);                   \
        unsigned bits0_ = (unsigned)(mw0 >> sh2_) & 0xffu;          \
        unsigned bits1_ = (unsigned)(mw1 >> sh2_) & 0xffu;          \
        int sb_ = jq * 1024 + (JT) * 32 + lg * 8;                   \
        f32x4 sA_ = *(const f32x4*)&s2_lds[sb_];                    \
        f32x4 sB_ = *(const f32x4*)&s2_lds[sb_ + 4];                \
        half8 ph0_, ph1_;                                           \
        _Pragma("unroll")                                           \
        for (int q_ = 0; q_ < 8; q_++) {                            \
            float sv_ = q_ < 4 ? sA_[q_ & 3] : sB_[q_ & 3];         \
            float s_ = s1r0 + sv_;                                  \
            float ev_ = fmaxf(s_, ALPHA * s_);                      \
            float p_ = ((bits0_ >> q_) & 1) ? __expf(ev_ - m0) : 0.f; \
            l0 += p_; ph0_[q_] = (f16)p_;                           \
            float t_ = s1r1 + sv_;                                  \
            float eu_ = fmaxf(t_, ALPHA * t_);                      \
            float u_ = ((bits1_ >> q_) & 1) ? __expf(eu_ - m1) : 0.f; \
            l1 += u_; ph1_[q_] = (f16)u_;                           \
        }                                                           \
        _Pragma("unroll")                                           \
        for (int ot_ = 0; ot_ < 8; ot_++) {                         \
            acc0[ot_] = __builtin_amdgcn_mfma_f32_16x16x32_f16(ph0_, BFC[ot_], acc0[ot_], 0, 0, 0); \
            acc1[ot_] = __builtin_amdgcn_mfma_f32_16x16x32_f16(ph1_, BFC[ot_], acc1[ot_], 0, 0, 0); \
        }                                                           \
    }

__global__ __launch_bounds__(512, 2) void k_attn(const unsigned long long* __restrict__ mask,
                                                 const f16* __restrict__ WhT,
                                                 const float* __restrict__ s1g,
                                                 const float* __restrict__ s2g,
                                                 const float* __restrict__ mg,
                                                 float* __restrict__ out) {
    __shared__ float s2_lds[NTOK];           // 8 KB
    __shared__ float accx[2][32][260];       // 66.6 KB: [jq][row in rg-group][col]
    __shared__ float lpart[2][64];           // [jq][row in block]

    int b = blockIdx.x & 7;                  // batch -> XCD pinning
    int i0 = (blockIdx.x >> 3) * 64;
    int t = threadIdx.x;
    int lane = t & 63, w = t >> 6;
    int jq = w & 1, oh = (w >> 1) & 1, rg = w >> 2;
    int lr = lane & 15, lg = lane >> 4;

    ((f32x4*)s2_lds)[t] = ((const f32x4*)(s2g + (size_t)b * NTOK))[t];
    __syncthreads();

    int r0 = i0 + rg * 32 + lr, r1 = r0 + 16;
    float s1r0 = s1g[(size_t)b * NTOK + r0];
    float s1r1 = s1g[(size_t)b * NTOK + r1];
    float m0 = mg[(size_t)b * NTOK + r0];
    float m1 = mg[(size_t)b * NTOK + r1];

    const unsigned long long* mr0 = mask + ((size_t)(b * NTOK + r0)) * 32 + jq * 16;
    const unsigned long long* mr1 = mask + ((size_t)(b * NTOK + r1)) * 32 + jq * 16;
    const f16* wb = WhT + ((size_t)(b * FOUT + oh * 128 + lr)) * WHS + jq * 1024 + lg * 8;

    f32x4 acc0[8] = {}, acc1[8] = {};
    float l0 = 0.f, l1 = 0.f;

    half8 bfA[8], bfB[8];
    LOADB(bfA, 0);
    unsigned long long mw0 = mr0[0], mw1 = mr1[0];
    unsigned long long nx0 = 0, nx1 = 0;

    for (int jt2 = 0; jt2 < 16; jt2++) {
        int jt = jt2 * 2;
        LOADB(bfB, jt + 1);                       // prefetch for odd sub-iter
        if (jt2 < 15) { nx0 = mr0[jt2 + 1]; nx1 = mr1[jt2 + 1]; }
        SUBITER(jt, bfA);
        if (jt2 < 15) LOADB(bfA, jt + 2);         // prefetch for next even
        SUBITER(jt + 1, bfB);
        mw0 = nx0; mw1 = nx1;
    }

    // per-row l: sum over the 4 k-lane-groups
    l0 += __shfl_xor(l0, 16); l0 += __shfl_xor(l0, 32);
    l1 += __shfl_xor(l1, 16); l1 += __shfl_xor(l1, 32);
    if (oh == 0 && lane < 16) {
        lpart[jq][rg * 32 + lr] = l0;
        lpart[jq][rg * 32 + 16 + lr] = l1;
    }
    __syncthreads();

    // combine jq halves (plain ADD — fixed shift), one rg-group per round
#pragma unroll
    for (int rr = 0; rr < 2; rr++) {
        if (rg == rr) {
#pragma unroll
            for (int ot = 0; ot < 8; ot++)
#pragma unroll
                for (int q = 0; q < 4; q++) {
                    accx[jq][lg * 4 + q][oh * 128 + ot * 16 + lr] = acc0[ot][q];
                    accx[jq][16 + lg * 4 + q][oh * 128 + ot * 16 + lr] = acc1[ot][q];
                }
        }
        __syncthreads();
        {
            int row = w * 4 + lg;                 // 0..31
            int c = lr * 16;
            float rl = 1.f / (lpart[0][rr * 32 + row] + lpart[1][rr * 32 + row]);
            float* op = out + ((size_t)(b * NTOK + i0 + rr * 32 + row)) * FOUT + c;
#pragma unroll
            for (int v4 = 0; v4 < 4; v4++) {
                f32x4 va = *(const f32x4*)&accx[0][row][c + v4 * 4] +
                           *(const f32x4*)&accx[1][row][c + v4 * 4];
                f32x4 oa;
#pragma unroll
                for (int q = 0; q < 4; q++) {
                    float u = va[q] * rl;
                    oa[q] = u > 0.f ? u : __expf(u) - 1.f;
                }
                __builtin_nontemporal_store(oa, (f32x4*)(op + v4 * 4));
            }
        }
        __syncthreads();
    }
}

extern "C" void kernel_launch(void* const* d_in, const int* in_sizes, int n_in,
                              void* d_out, int out_size, void* d_ws, size_t ws_size,
                              hipStream_t stream) {
    const float* x = (const float*)d_in[0];
    const int* adj = (const int*)d_in[1];
    const float* W = (const float*)d_in[2];
    const float* a = (const float*)d_in[3];
    float* out = (float*)d_out;

    char* ws = (char*)d_ws;
    f16* WT = (f16*)ws;                                     // 128 KB
    f16* WhT = (f16*)(ws + 131072);                         // 8.13 MB
    float* s1 = (float*)(ws + 131072 + 8519680);            // 64 KB
    float* s2 = s1 + BATCH * NTOK;                          // 64 KB
    float* mrow = s2 + BATCH * NTOK;                        // 64 KB
    unsigned long long* mask64 =
        (unsigned long long*)(ws + 131072 + 8519680 + 196608);  // 4 MB

    k_wt<<<dim3(FOUT / 32, FIN / 32), dim3(32, 32), 0, stream>>>(W, WT);
    k_gemm<<<dim3(BATCH * NTOK / 64), 256, 0, stream>>>(x, WT, WhT);
    k_s12<<<dim3(NTOK / 256, BATCH), 256, 0, stream>>>(WhT, a, s1, s2);
    k_rowmax<<<dim3(BATCH), 256, 0, stream>>>(s1, s2, mrow);
    k_pack<<<dim3(4096), 256, 0, stream>>>(adj, mask64);
    k_attn<<<dim3(BATCH * NTOK / 32 / 2), 512, 0, stream>>>(mask64, WhT, s1, s2, mrow, out);
}

// Round 10
// 119.978 us; speedup vs baseline: 1.1473x; 1.1473x over previous
//
#include <hip/hip_runtime.h>
#include <hip/hip_fp16.h>

typedef _Float16 f16;
typedef _Float16 half4 __attribute__((ext_vector_type(4)));
typedef _Float16 half8 __attribute__((ext_vector_type(8)));
typedef float f32x4 __attribute__((ext_vector_type(4)));

#define BATCH 8
#define NTOK 2048
#define FIN 256
#define FOUT 256
#define ALPHA 0.2f

// WhT swizzled layout: [b][slab(32)][o(256)][u(8)][q(8)] f16, where the
// logical element Wh[n][o] (n = slab*64 + jg8*8 + jq) lives at
// u = jg8 ^ (o & 7).  Each slab is a contiguous 32 KB block == LDS image.

__device__ __forceinline__ void gload16(const void* g, void* l) {
    __builtin_amdgcn_global_load_lds(
        (const __attribute__((address_space(1))) unsigned int*)(g),
        (__attribute__((address_space(3))) unsigned int*)(l), 16, 0, 0);
}

// ---------------- K0: W[k][o] fp32 -> WT[o][k] fp16 ----------------
__global__ void k_wt(const float* __restrict__ W, f16* __restrict__ WT) {
    __shared__ float t[32][33];
    int o0 = blockIdx.x * 32, k0 = blockIdx.y * 32;
    int tx = threadIdx.x, ty = threadIdx.y;
    t[ty][tx] = W[(k0 + ty) * FOUT + o0 + tx];
    __syncthreads();
    WT[(o0 + ty) * FIN + (k0 + tx)] = (f16)t[tx][ty];
}

// ---------------- K pack: adj int32 -> bitmask (dedicated streamer) ----------------
__global__ __launch_bounds__(256) void k_pack(const int* __restrict__ adj,
                                              unsigned long long* __restrict__ mask) {
    int lane = threadIdx.x & 63;
    size_t wv = (((size_t)blockIdx.x * 256 + threadIdx.x) >> 6);
    for (int it = 0; it < 8; it++) {
        size_t wave = wv + (size_t)it * 16384;
        const int* base = adj + wave * 256;
        unsigned long long m0 = __ballot(base[lane] > 0);
        unsigned long long m1 = __ballot(base[64 + lane] > 0);
        unsigned long long m2 = __ballot(base[128 + lane] > 0);
        unsigned long long m3 = __ballot(base[192 + lane] > 0);
        if (lane < 4) {
            unsigned long long v = lane == 0 ? m0 : lane == 1 ? m1 : lane == 2 ? m2 : m3;
            mask[wave * 4 + lane] = v;
        }
    }
}

// ---------------- K1: Wh = x @ W -> swizzled WhT ----------------
__global__ __launch_bounds__(256) void k_gemm(const float* __restrict__ x,
                                              const f16* __restrict__ WT,
                                              f16* __restrict__ WhT) {
    __shared__ f16 Ah[64][72];
    __shared__ f16 Bt[256][72];
    int m0 = blockIdx.x * 64;
    int t = threadIdx.x;
    int lane = t & 63, w = t >> 6;
    int lr = lane & 15, lg = lane >> 4;
    f32x4 acc[4][4] = {};

    for (int k0 = 0; k0 < FIN; k0 += 64) {
        {
            int r = t >> 2, c = (t & 3) * 16;
            const float* src = x + (size_t)(m0 + r) * FIN + k0 + c;
            f16 tmp[16];
#pragma unroll
            for (int q = 0; q < 16; q++) tmp[q] = (f16)src[q];
            *(half8*)&Ah[r][c] = *(half8*)&tmp[0];
            *(half8*)&Ah[r][c + 8] = *(half8*)&tmp[8];
        }
        {
            const f16* src = WT + (size_t)t * FIN + k0;
#pragma unroll
            for (int q = 0; q < 8; q++)
                *(half8*)&Bt[t][q * 8] = *(const half8*)&src[q * 8];
        }
        __syncthreads();
#pragma unroll
        for (int kc = 0; kc < 2; kc++) {
            int krow = kc * 32 + lg * 8;
            half8 af[4], bf[4];
#pragma unroll
            for (int fi = 0; fi < 4; fi++)
                af[fi] = *(half8*)&Ah[fi * 16 + lr][krow];
#pragma unroll
            for (int fo = 0; fo < 4; fo++)
                bf[fo] = *(half8*)&Bt[w * 64 + fo * 16 + lr][krow];
#pragma unroll
            for (int fi = 0; fi < 4; fi++)
#pragma unroll
                for (int fo = 0; fo < 4; fo++)
                    acc[fi][fo] = __builtin_amdgcn_mfma_f32_16x16x32_f16(
                        af[fi], bf[fo], acc[fi][fo], 0, 0, 0);
        }
        __syncthreads();
    }
    int b = m0 >> 11;
    int slab = (m0 & (NTOK - 1)) >> 6;
    f16* wdst = WhT + ((size_t)(b * 32 + slab) * 256) * 64;
    int jq0 = (lg & 1) * 4;
#pragma unroll
    for (int fi = 0; fi < 4; fi++) {
        int jg8 = fi * 2 + (lg >> 1);
#pragma unroll
        for (int fo = 0; fo < 4; fo++) {
            int o = w * 64 + fo * 16 + lr;
            half4 hv;
#pragma unroll
            for (int q = 0; q < 4; q++) hv[q] = (f16)acc[fi][fo][q];
            *(half4*)(wdst + o * 64 + ((jg8 ^ (o & 7)) * 8) + jq0) = hv;
        }
    }
}

// ---------------- K2: s1 = Wh@a1, s2 = Wh@a2 (swizzled layout reads) ----------------
__global__ __launch_bounds__(256) void k_s12(const f16* __restrict__ WhT,
                                             const float* __restrict__ a,
                                             float* __restrict__ s1,
                                             float* __restrict__ s2) {
    int b = blockIdx.y;
    int n = blockIdx.x * 256 + threadIdx.x;
    const f16* base = WhT + ((size_t)(b * 32 + (n >> 6)) * 256) * 64;
    int jg8 = (n >> 3) & 7, jq = n & 7;
    float a1 = 0.f, a2 = 0.f;
#pragma unroll 4
    for (int o = 0; o < FOUT; o++) {
        float wh = (float)base[o * 64 + ((jg8 ^ (o & 7)) * 8) + jq];
        a1 += wh * a[o];
        a2 += wh * a[FOUT + o];
    }
    s1[b * NTOK + n] = a1;
    s2[b * NTOK + n] = a2;
}

// ---------------- K2b: mrow[b][i] = lrelu(s1[b][i] + max_j s2[b][j]) ----------------
__global__ __launch_bounds__(256) void k_rowmax(const float* __restrict__ s1,
                                                const float* __restrict__ s2,
                                                float* __restrict__ mrow) {
    __shared__ float red[4];
    int b = blockIdx.x, t = threadIdx.x;
    const float* s2b = s2 + (size_t)b * NTOK;
    float mx = -3.0e38f;
#pragma unroll
    for (int i = 0; i < 8; i++) mx = fmaxf(mx, s2b[t + i * 256]);
#pragma unroll
    for (int d = 1; d < 64; d <<= 1) mx = fmaxf(mx, __shfl_xor(mx, d));
    if ((t & 63) == 0) red[t >> 6] = mx;
    __syncthreads();
    float s2m = fmaxf(fmaxf(red[0], red[1]), fmaxf(red[2], red[3]));
#pragma unroll
    for (int i = 0; i < 8; i++) {
        int n = t + i * 256;
        float s = s1[(size_t)b * NTOK + n] + s2m;
        mrow[(size_t)b * NTOK + n] = fmaxf(s, ALPHA * s);
    }
}

// ---------------- K3: fused softmax(fixed shift) + P@Wh + ELU ----------------
// 64-row blocks, 8 waves = js(2: 32-j half of each slab) x oh(2: 128-o) x
// rg(2: 32-row group, 2 A-tiles fi=0/1). Per 64-j step: WhT slab (32 KB)
// DMA-staged via global_load_lds into double-buffered LINEAR LDS (source
// pre-swizzled, reads XOR-deswizzle -> conflict-free b128). One barrier/step,
// stage issued a full step ahead, zero VGPR cost for staging.
__global__ __launch_bounds__(512, 2) void k_attn(const unsigned* __restrict__ mask32,
                                                 const f16* __restrict__ WhT,
                                                 const float* __restrict__ s1g,
                                                 const float* __restrict__ s2g,
                                                 const float* __restrict__ mg,
                                                 float* __restrict__ out) {
    __shared__ __align__(16) char smem[65536 + 8192 + 512];
    f16* Bl = (f16*)smem;                          // [2][16384] f16 (2x32KB)
    float* s2_lds = (float*)(smem + 65536);        // [2048]
    float* lpart = (float*)(smem + 65536 + 8192);  // [2][64]

    int b = blockIdx.x & 7;                        // batch -> XCD pinning
    int i0 = (blockIdx.x >> 3) * 64;
    int t = threadIdx.x;
    int lane = t & 63, w = t >> 6;
    int js = w & 1, oh = (w >> 1) & 1, rg = w >> 2;
    int lr = lane & 15, lg = lane >> 4;

    ((f32x4*)s2_lds)[t] = ((const f32x4*)(s2g + (size_t)b * NTOK))[t];

    const char* wsrc = (const char*)WhT + (size_t)b * (32 * 32768);
    // prologue: stage slab 0 into buf 0
    {
        const char* src = wsrc + (w * 4) * 1024 + lane * 16;
        char* dst = (char*)Bl + (w * 4) * 1024;
#pragma unroll
        for (int k = 0; k < 4; k++) gload16(src + k * 1024, dst + k * 1024);
    }

    int r0 = i0 + rg * 32 + lr, r1 = r0 + 16;
    float s1r0 = s1g[(size_t)b * NTOK + r0];
    float s1r1 = s1g[(size_t)b * NTOK + r1];
    float mx0 = mg[(size_t)b * NTOK + r0];
    float mx1 = mg[(size_t)b * NTOK + r1];
    const unsigned* mr0 = mask32 + (size_t)(b * NTOK + r0) * 64 + js;
    const unsigned* mr1 = mask32 + (size_t)(b * NTOK + r1) * 64 + js;

    f32x4 acc0[8] = {}, acc1[8] = {};
    float l0 = 0.f, l1 = 0.f;
    int rswz = ((js * 4 + lg) ^ (lr & 7)) * 8;     // deswizzled j-unit offset (f16)

    __syncthreads();                                // s2 + slab0 staged (vmcnt drain)

    for (int s = 0; s < 32; s++) {
        int buf = s & 1;
        if (s < 31) {                               // stage next slab -> other buf
            const char* src = wsrc + (size_t)(s + 1) * 32768 + (w * 4) * 1024 + lane * 16;
            char* dst = (char*)Bl + (buf ^ 1) * 32768 + (w * 4) * 1024;
#pragma unroll
            for (int k = 0; k < 4; k++) gload16(src + k * 1024, dst + k * 1024);
        }

        unsigned bw0 = mr0[s * 2], bw1 = mr1[s * 2];
        unsigned bits0 = (bw0 >> (lg * 8)) & 0xffu;
        unsigned bits1 = (bw1 >> (lg * 8)) & 0xffu;

        int sb = s * 64 + js * 32 + lg * 8;
        f32x4 sA = *(const f32x4*)&s2_lds[sb];
        f32x4 sB = *(const f32x4*)&s2_lds[sb + 4];

        half8 ph0, ph1;
#pragma unroll
        for (int q = 0; q < 8; q++) {
            float sv = q < 4 ? sA[q & 3] : sB[q & 3];
            float sx = s1r0 + sv;
            float ev = fmaxf(sx, ALPHA * sx);
            float p = ((bits0 >> q) & 1) ? __expf(ev - mx0) : 0.f;
            l0 += p; ph0[q] = (f16)p;
            float sy = s1r1 + sv;
            float eu = fmaxf(sy, ALPHA * sy);
            float u = ((bits1 >> q) & 1) ? __expf(eu - mx1) : 0.f;
            l1 += u; ph1[q] = (f16)u;
        }

        const f16* bbase = Bl + buf * 16384 + (oh * 128 + lr) * 64 + rswz;
#pragma unroll
        for (int ot = 0; ot < 8; ot++) {
            half8 bf = *(const half8*)(bbase + ot * (16 * 64));
            acc0[ot] = __builtin_amdgcn_mfma_f32_16x16x32_f16(ph0, bf, acc0[ot], 0, 0, 0);
            acc1[ot] = __builtin_amdgcn_mfma_f32_16x16x32_f16(ph1, bf, acc1[ot], 0, 0, 0);
        }
        __syncthreads();
    }

    // l reduce over the 4 lg-groups (js halves add later; fixed shift)
    l0 += __shfl_xor(l0, 16); l0 += __shfl_xor(l0, 32);
    l1 += __shfl_xor(l1, 16); l1 += __shfl_xor(l1, 32);
    if (oh == 0 && lg == 0) {
        lpart[js * 64 + rg * 32 + lr] = l0;
        lpart[js * 64 + rg * 32 + 16 + lr] = l1;
    }
    __syncthreads();

    // combine js halves via LDS (aliases Bl), then divide + ELU + store
    float* accx = (float*)smem;                     // [64][260]
    if (js == 1) {
#pragma unroll
        for (int ot = 0; ot < 8; ot++)
#pragma unroll
            for (int q = 0; q < 4; q++) {
                accx[(rg * 32 + lg * 4 + q) * 260 + oh * 128 + ot * 16 + lr] = acc0[ot][q];
                accx[(rg * 32 + 16 + lg * 4 + q) * 260 + oh * 128 + ot * 16 + lr] = acc1[ot][q];
            }
    }
    __syncthreads();
    if (js == 0) {
        f32x4 rl0, rl1;
#pragma unroll
        for (int q = 0; q < 4; q++) {
            int ra = rg * 32 + lg * 4 + q, rb = ra + 16;
            rl0[q] = 1.f / (lpart[ra] + lpart[64 + ra]);
            rl1[q] = 1.f / (lpart[rb] + lpart[64 + rb]);
        }
#pragma unroll
        for (int ot = 0; ot < 8; ot++) {
            int o = oh * 128 + ot * 16 + lr;
#pragma unroll
            for (int q = 0; q < 4; q++) {
                int ra = rg * 32 + lg * 4 + q;
                float u = (acc0[ot][q] + accx[ra * 260 + o]) * rl0[q];
                u = u > 0.f ? u : __expf(u) - 1.f;
                __builtin_nontemporal_store(u, &out[((size_t)(b * NTOK + i0 + ra)) * FOUT + o]);
                int rb = ra + 16;
                float v = (acc1[ot][q] + accx[rb * 260 + o]) * rl1[q];
                v = v > 0.f ? v : __expf(v) - 1.f;
                __builtin_nontemporal_store(v, &out[((size_t)(b * NTOK + i0 + rb)) * FOUT + o]);
            }
        }
    }
}

extern "C" void kernel_launch(void* const* d_in, const int* in_sizes, int n_in,
                              void* d_out, int out_size, void* d_ws, size_t ws_size,
                              hipStream_t stream) {
    const float* x = (const float*)d_in[0];
    const int* adj = (const int*)d_in[1];
    const float* W = (const float*)d_in[2];
    const float* a = (const float*)d_in[3];
    float* out = (float*)d_out;

    char* ws = (char*)d_ws;
    f16* WT = (f16*)ws;                                     // 128 KB
    f16* WhT = (f16*)(ws + 131072);                         // 8 MB swizzled
    float* s1 = (float*)(ws + 131072 + 8388608);            // 64 KB
    float* s2 = s1 + BATCH * NTOK;                          // 64 KB
    float* mrow = s2 + BATCH * NTOK;                        // 64 KB
    unsigned long long* mask64 =
        (unsigned long long*)(ws + 131072 + 8388608 + 196608);  // 4 MB

    k_wt<<<dim3(FOUT / 32, FIN / 32), dim3(32, 32), 0, stream>>>(W, WT);
    k_gemm<<<dim3(BATCH * NTOK / 64), 256, 0, stream>>>(x, WT, WhT);
    k_s12<<<dim3(NTOK / 256, BATCH), 256, 0, stream>>>(WhT, a, s1, s2);
    k_rowmax<<<dim3(BATCH), 256, 0, stream>>>(s1, s2, mrow);
    k_pack<<<dim3(4096), 256, 0, stream>>>(adj, mask64);
    k_attn<<<dim3(BATCH * NTOK / 64), 512, 0, stream>>>((const unsigned*)mask64, WhT,
                                                        s1, s2, mrow, out);
}

// Round 11
// 97.138 us; speedup vs baseline: 1.4171x; 1.2351x over previous
//
#include <hip/hip_runtime.h>
#include <hip/hip_fp16.h>

typedef _Float16 f16;
typedef _Float16 half4 __attribute__((ext_vector_type(4)));
typedef _Float16 half8 __attribute__((ext_vector_type(8)));
typedef float f32x4 __attribute__((ext_vector_type(4)));

#define BATCH 8
#define NTOK 2048
#define FIN 256
#define FOUT 256
#define ALPHA 0.2f

// WhT swizzled layout: [b][slab(32)][o(256)][u(8)][q(8)] f16; logical
// Wh[n][o] (n = slab*64 + jg8*8 + jq) lives at u = jg8 ^ (o & 7).
// Each slab is a contiguous 32 KB block == its LDS image in k_attn.

__device__ __forceinline__ void gload16(const void* g, void* l) {
    __builtin_amdgcn_global_load_lds(
        (const __attribute__((address_space(1))) unsigned int*)(g),
        (__attribute__((address_space(3))) unsigned int*)(l), 16, 0, 0);
}

// ---------------- K0: W[k][o] fp32 -> WT[o][k] fp16 ----------------
__global__ void k_wt(const float* __restrict__ W, f16* __restrict__ WT) {
    __shared__ float t[32][33];
    int o0 = blockIdx.x * 32, k0 = blockIdx.y * 32;
    int tx = threadIdx.x, ty = threadIdx.y;
    t[ty][tx] = W[(k0 + ty) * FOUT + o0 + tx];
    __syncthreads();
    WT[(o0 + ty) * FIN + (k0 + tx)] = (f16)t[tx][ty];
}

// ---------------- K1: FUSED  gemm(+s1/s2 epilogue)  ||  adj->bitmask pack ----------------
// blocks 0..255: Wh = x@W -> swizzled WhT slab + s1/s2 from fp32 acc.
// blocks 256..4351: pack adj into bitmask (pure streaming, overlaps gemm).
__global__ __launch_bounds__(256) void k_gp(const float* __restrict__ x,
                                            const f16* __restrict__ WT,
                                            const int* __restrict__ adj,
                                            f16* __restrict__ WhT,
                                            unsigned long long* __restrict__ mask,
                                            const float* __restrict__ a,
                                            float* __restrict__ s1,
                                            float* __restrict__ s2) {
    __shared__ __align__(16) char gsmem[46080];
    int t = threadIdx.x;

    if (blockIdx.x >= 256) {            // ---- pack branch ----
        int lane = t & 63;
        size_t wv = (((size_t)(blockIdx.x - 256) * 256 + t) >> 6);
        for (int it = 0; it < 8; it++) {
            size_t wave = wv + (size_t)it * 16384;
            const int* base = adj + wave * 256;
            unsigned long long m0 = __ballot(base[lane] > 0);
            unsigned long long m1 = __ballot(base[64 + lane] > 0);
            unsigned long long m2 = __ballot(base[128 + lane] > 0);
            unsigned long long m3 = __ballot(base[192 + lane] > 0);
            if (lane < 4) {
                unsigned long long v = lane == 0 ? m0 : lane == 1 ? m1 : lane == 2 ? m2 : m3;
                mask[wave * 4 + lane] = v;
            }
        }
        return;
    }

    // ---- gemm branch ----
    f16* Ah = (f16*)gsmem;               // [64][72]
    f16* Bt = (f16*)(gsmem + 9216);      // [256][72]
    int m0 = blockIdx.x * 64;
    int lane = t & 63, w = t >> 6;
    int lr = lane & 15, lg = lane >> 4;
    f32x4 acc[4][4] = {};

    for (int k0 = 0; k0 < FIN; k0 += 64) {
        {
            int r = t >> 2, c = (t & 3) * 16;
            const float* src = x + (size_t)(m0 + r) * FIN + k0 + c;
            f32x4 v0 = *(const f32x4*)(src);
            f32x4 v1 = *(const f32x4*)(src + 4);
            f32x4 v2 = *(const f32x4*)(src + 8);
            f32x4 v3 = *(const f32x4*)(src + 12);
            half8 h0, h1;
#pragma unroll
            for (int q = 0; q < 4; q++) {
                h0[q] = (f16)v0[q]; h0[q + 4] = (f16)v1[q];
                h1[q] = (f16)v2[q]; h1[q + 4] = (f16)v3[q];
            }
            f16* dst = Ah + r * 72 + c;
            *(half8*)dst = h0;
            *(half8*)(dst + 8) = h1;
        }
        {
            const f16* src = WT + (size_t)t * FIN + k0;
            f16* dst = Bt + t * 72;
#pragma unroll
            for (int q = 0; q < 8; q++)
                *(half8*)(dst + q * 8) = *(const half8*)(src + q * 8);
        }
        __syncthreads();
#pragma unroll
        for (int kc = 0; kc < 2; kc++) {
            int krow = kc * 32 + lg * 8;
            half8 af[4], bf[4];
#pragma unroll
            for (int fi = 0; fi < 4; fi++)
                af[fi] = *(half8*)(Ah + (fi * 16 + lr) * 72 + krow);
#pragma unroll
            for (int fo = 0; fo < 4; fo++)
                bf[fo] = *(half8*)(Bt + (w * 64 + fo * 16 + lr) * 72 + krow);
#pragma unroll
            for (int fi = 0; fi < 4; fi++)
#pragma unroll
                for (int fo = 0; fo < 4; fo++)
                    acc[fi][fo] = __builtin_amdgcn_mfma_f32_16x16x32_f16(
                        af[fi], bf[fo], acc[fi][fo], 0, 0, 0);
        }
        __syncthreads();
    }

    int b = m0 >> 11;
    int slab_i = (m0 & (NTOK - 1)) >> 6;
    int nbase = m0 & (NTOK - 1);

    // s1/s2 partials from fp32 acc (o-range fully inside block)
    float* sred = (float*)gsmem;          // [2][4][64] floats (aliases Ah)
    f16* slab = (f16*)(gsmem + 9216);     // 32 KB slab image (aliases Bt)
    float a1v[4], a2v[4];
#pragma unroll
    for (int fo = 0; fo < 4; fo++) {
        int o = w * 64 + fo * 16 + lr;
        a1v[fo] = a[o];
        a2v[fo] = a[FOUT + o];
    }
#pragma unroll
    for (int fi = 0; fi < 4; fi++) {
        f32x4 p1 = {}, p2 = {};
#pragma unroll
        for (int fo = 0; fo < 4; fo++) {
            p1 += acc[fi][fo] * a1v[fo];
            p2 += acc[fi][fo] * a2v[fo];
        }
#pragma unroll
        for (int q = 0; q < 4; q++) {
#pragma unroll
            for (int d = 1; d < 16; d <<= 1) {
                p1[q] += __shfl_xor(p1[q], d);
                p2[q] += __shfl_xor(p2[q], d);
            }
        }
        if (lr == 0) {
            int row = fi * 16 + lg * 4;
#pragma unroll
            for (int q = 0; q < 4; q++) {
                sred[w * 64 + row + q] = p1[q];
                sred[256 + w * 64 + row + q] = p2[q];
            }
        }
    }
    // swizzled f16 slab image into LDS
#pragma unroll
    for (int fi = 0; fi < 4; fi++) {
        int jg8 = fi * 2 + (lg >> 1), jq0 = (lg & 1) * 4;
#pragma unroll
        for (int fo = 0; fo < 4; fo++) {
            int o = w * 64 + fo * 16 + lr;
            half4 hv;
#pragma unroll
            for (int q = 0; q < 4; q++) hv[q] = (f16)acc[fi][fo][q];
            *(half4*)(slab + o * 64 + ((jg8 ^ (o & 7)) * 8) + jq0) = hv;
        }
    }
    __syncthreads();

    if (t < 64) {
        s1[(size_t)b * NTOK + nbase + t] =
            sred[t] + sred[64 + t] + sred[128 + t] + sred[192 + t];
    } else if (t < 128) {
        int r2 = t - 64;
        s2[(size_t)b * NTOK + nbase + r2] =
            sred[256 + r2] + sred[320 + r2] + sred[384 + r2] + sred[448 + r2];
    }
    // coalesced slab copy-out (layout identical to LDS image)
    {
        const int4* sl = (const int4*)slab;
        int4* gd = (int4*)(WhT + ((size_t)(b * 32 + slab_i) * 256) * 64);
#pragma unroll
        for (int i = 0; i < 8; i++) gd[i * 256 + t] = sl[i * 256 + t];
    }
}

// ---------------- K2b: mrow[b][i] = lrelu(s1[b][i] + max_j s2[b][j]) ----------------
__global__ __launch_bounds__(256) void k_rowmax(const float* __restrict__ s1,
                                                const float* __restrict__ s2,
                                                float* __restrict__ mrow) {
    __shared__ float red[4];
    int b = blockIdx.x, t = threadIdx.x;
    const float* s2b = s2 + (size_t)b * NTOK;
    float mx = -3.0e38f;
#pragma unroll
    for (int i = 0; i < 8; i++) mx = fmaxf(mx, s2b[t + i * 256]);
#pragma unroll
    for (int d = 1; d < 64; d <<= 1) mx = fmaxf(mx, __shfl_xor(mx, d));
    if ((t & 63) == 0) red[t >> 6] = mx;
    __syncthreads();
    float s2m = fmaxf(fmaxf(red[0], red[1]), fmaxf(red[2], red[3]));
#pragma unroll
    for (int i = 0; i < 8; i++) {
        int n = t + i * 256;
        float s = s1[(size_t)b * NTOK + n] + s2m;
        mrow[(size_t)b * NTOK + n] = fmaxf(s, ALPHA * s);
    }
}

// ---------------- K3: fused softmax(fixed shift) + P@Wh + ELU ----------------
// (R10 structure, validated; + mask words prefetched one step ahead)
__global__ __launch_bounds__(512, 2) void k_attn(const unsigned* __restrict__ mask32,
                                                 const f16* __restrict__ WhT,
                                                 const float* __restrict__ s1g,
                                                 const float* __restrict__ s2g,
                                                 const float* __restrict__ mg,
                                                 float* __restrict__ out) {
    __shared__ __align__(16) char smem[65536 + 8192 + 512];
    f16* Bl = (f16*)smem;                          // [2][16384] f16 (2x32KB)
    float* s2_lds = (float*)(smem + 65536);        // [2048]
    float* lpart = (float*)(smem + 65536 + 8192);  // [2][64]

    int b = blockIdx.x & 7;                        // batch -> XCD pinning
    int i0 = (blockIdx.x >> 3) * 64;
    int t = threadIdx.x;
    int lane = t & 63, w = t >> 6;
    int js = w & 1, oh = (w >> 1) & 1, rg = w >> 2;
    int lr = lane & 15, lg = lane >> 4;

    ((f32x4*)s2_lds)[t] = ((const f32x4*)(s2g + (size_t)b * NTOK))[t];

    const char* wsrc = (const char*)WhT + (size_t)b * (32 * 32768);
    {
        const char* src = wsrc + (w * 4) * 1024 + lane * 16;
        char* dst = (char*)Bl + (w * 4) * 1024;
#pragma unroll
        for (int k = 0; k < 4; k++) gload16(src + k * 1024, dst + k * 1024);
    }

    int r0 = i0 + rg * 32 + lr, r1 = r0 + 16;
    float s1r0 = s1g[(size_t)b * NTOK + r0];
    float s1r1 = s1g[(size_t)b * NTOK + r1];
    float mx0 = mg[(size_t)b * NTOK + r0];
    float mx1 = mg[(size_t)b * NTOK + r1];
    const unsigned* mr0 = mask32 + (size_t)(b * NTOK + r0) * 64 + js;
    const unsigned* mr1 = mask32 + (size_t)(b * NTOK + r1) * 64 + js;

    f32x4 acc0[8] = {}, acc1[8] = {};
    float l0 = 0.f, l1 = 0.f;
    int rswz = ((js * 4 + lg) ^ (lr & 7)) * 8;

    unsigned bw0 = mr0[0], bw1 = mr1[0];

    __syncthreads();                                // s2 + slab0 staged

    for (int s = 0; s < 32; s++) {
        int buf = s & 1;
        if (s < 31) {
            const char* src = wsrc + (size_t)(s + 1) * 32768 + (w * 4) * 1024 + lane * 16;
            char* dst = (char*)Bl + (buf ^ 1) * 32768 + (w * 4) * 1024;
#pragma unroll
            for (int k = 0; k < 4; k++) gload16(src + k * 1024, dst + k * 1024);
        }

        unsigned cw0 = bw0, cw1 = bw1;
        if (s < 31) { bw0 = mr0[(s + 1) * 2]; bw1 = mr1[(s + 1) * 2]; }
        unsigned bits0 = (cw0 >> (lg * 8)) & 0xffu;
        unsigned bits1 = (cw1 >> (lg * 8)) & 0xffu;

        int sb = s * 64 + js * 32 + lg * 8;
        f32x4 sA = *(const f32x4*)&s2_lds[sb];
        f32x4 sB = *(const f32x4*)&s2_lds[sb + 4];

        half8 ph0, ph1;
#pragma unroll
        for (int q = 0; q < 8; q++) {
            float sv = q < 4 ? sA[q & 3] : sB[q & 3];
            float sx = s1r0 + sv;
            float ev = fmaxf(sx, ALPHA * sx);
            float p = ((bits0 >> q) & 1) ? __expf(ev - mx0) : 0.f;
            l0 += p; ph0[q] = (f16)p;
            float sy = s1r1 + sv;
            float eu = fmaxf(sy, ALPHA * sy);
            float u = ((bits1 >> q) & 1) ? __expf(eu - mx1) : 0.f;
            l1 += u; ph1[q] = (f16)u;
        }

        const f16* bbase = Bl + buf * 16384 + (oh * 128 + lr) * 64 + rswz;
#pragma unroll
        for (int ot = 0; ot < 8; ot++) {
            half8 bf = *(const half8*)(bbase + ot * (16 * 64));
            acc0[ot] = __builtin_amdgcn_mfma_f32_16x16x32_f16(ph0, bf, acc0[ot], 0, 0, 0);
            acc1[ot] = __builtin_amdgcn_mfma_f32_16x16x32_f16(ph1, bf, acc1[ot], 0, 0, 0);
        }
        __syncthreads();
    }

    l0 += __shfl_xor(l0, 16); l0 += __shfl_xor(l0, 32);
    l1 += __shfl_xor(l1, 16); l1 += __shfl_xor(l1, 32);
    if (oh == 0 && lg == 0) {
        lpart[js * 64 + rg * 32 + lr] = l0;
        lpart[js * 64 + rg * 32 + 16 + lr] = l1;
    }
    __syncthreads();

    float* accx = (float*)smem;                     // [64][260]
    if (js == 1) {
#pragma unroll
        for (int ot = 0; ot < 8; ot++)
#pragma unroll
            for (int q = 0; q < 4; q++) {
                accx[(rg * 32 + lg * 4 + q) * 260 + oh * 128 + ot * 16 + lr] = acc0[ot][q];
                accx[(rg * 32 + 16 + lg * 4 + q) * 260 + oh * 128 + ot * 16 + lr] = acc1[ot][q];
            }
    }
    __syncthreads();
    if (js == 0) {
        f32x4 rl0, rl1;
#pragma unroll
        for (int q = 0; q < 4; q++) {
            int ra = rg * 32 + lg * 4 + q, rb = ra + 16;
            rl0[q] = 1.f / (lpart[ra] + lpart[64 + ra]);
            rl1[q] = 1.f / (lpart[rb] + lpart[64 + rb]);
        }
#pragma unroll
        for (int ot = 0; ot < 8; ot++) {
            int o = oh * 128 + ot * 16 + lr;
#pragma unroll
            for (int q = 0; q < 4; q++) {
                int ra = rg * 32 + lg * 4 + q;
                float u = (acc0[ot][q] + accx[ra * 260 + o]) * rl0[q];
                u = u > 0.f ? u : __expf(u) - 1.f;
                __builtin_nontemporal_store(u, &out[((size_t)(b * NTOK + i0 + ra)) * FOUT + o]);
                int rb = ra + 16;
                float v = (acc1[ot][q] + accx[rb * 260 + o]) * rl1[q];
                v = v > 0.f ? v : __expf(v) - 1.f;
                __builtin_nontemporal_store(v, &out[((size_t)(b * NTOK + i0 + rb)) * FOUT + o]);
            }
        }
    }
}

extern "C" void kernel_launch(void* const* d_in, const int* in_sizes, int n_in,
                              void* d_out, int out_size, void* d_ws, size_t ws_size,
                              hipStream_t stream) {
    const float* x = (const float*)d_in[0];
    const int* adj = (const int*)d_in[1];
    const float* W = (const float*)d_in[2];
    const float* a = (const float*)d_in[3];
    float* out = (float*)d_out;

    char* ws = (char*)d_ws;
    f16* WT = (f16*)ws;                                     // 128 KB
    f16* WhT = (f16*)(ws + 131072);                         // 8 MB swizzled
    float* s1 = (float*)(ws + 131072 + 8388608);            // 64 KB
    float* s2 = s1 + BATCH * NTOK;                          // 64 KB
    float* mrow = s2 + BATCH * NTOK;                        // 64 KB
    unsigned long long* mask64 =
        (unsigned long long*)(ws + 131072 + 8388608 + 196608);  // 4 MB

    k_wt<<<dim3(FOUT / 32, FIN / 32), dim3(32, 32), 0, stream>>>(W, WT);
    k_gp<<<dim3(256 + 4096), 256, 0, stream>>>(x, WT, adj, WhT, mask64, a, s1, s2);
    k_rowmax<<<dim3(BATCH), 256, 0, stream>>>(s1, s2, mrow);
    k_attn<<<dim3(BATCH * NTOK / 64), 512, 0, stream>>>((const unsigned*)mask64, WhT,
                                                        s1, s2, mrow, out);
}

// Round 12
// 89.491 us; speedup vs baseline: 1.5382x; 1.0854x over previous
//
#include <hip/hip_runtime.h>
#include <hip/hip_fp16.h>

typedef _Float16 f16;
typedef _Float16 half4 __attribute__((ext_vector_type(4)));
typedef _Float16 half8 __attribute__((ext_vector_type(8)));
typedef float f32x4 __attribute__((ext_vector_type(4)));

#define BATCH 8
#define NTOK 2048
#define FIN 256
#define FOUT 256
#define ALPHA 0.2f

// WhT swizzled layout: [b][slab(32)][o(256)][u(8)][q(8)] f16; logical
// Wh[n][o] (n = slab*64 + jg8*8 + jq) lives at u = jg8 ^ (o & 7).
// Each slab is a contiguous 32 KB block == its LDS image in k_attn.

__device__ __forceinline__ void gload16(const void* g, void* l) {
    __builtin_amdgcn_global_load_lds(
        (const __attribute__((address_space(1))) unsigned int*)(g),
        (__attribute__((address_space(3))) unsigned int*)(l), 16, 0, 0);
}

// ---------------- K0: W[k][o] fp32 -> WT[o][k] fp16 ----------------
__global__ void k_wt(const float* __restrict__ W, f16* __restrict__ WT) {
    __shared__ float t[32][33];
    int o0 = blockIdx.x * 32, k0 = blockIdx.y * 32;
    int tx = threadIdx.x, ty = threadIdx.y;
    t[ty][tx] = W[(k0 + ty) * FOUT + o0 + tx];
    __syncthreads();
    WT[(o0 + ty) * FIN + (k0 + tx)] = (f16)t[tx][ty];
}

// ---------------- K pack: adj int32 -> bitmask (standalone: 0 LDS, 8 blk/CU) ----------------
__global__ __launch_bounds__(256) void k_pack(const int* __restrict__ adj,
                                              unsigned long long* __restrict__ mask) {
    int lane = threadIdx.x & 63;
    size_t wv = (((size_t)blockIdx.x * 256 + threadIdx.x) >> 6);
    for (int it = 0; it < 8; it++) {
        size_t wave = wv + (size_t)it * 16384;
        const int* base = adj + wave * 256;
        unsigned long long m0 = __ballot(base[lane] > 0);
        unsigned long long m1 = __ballot(base[64 + lane] > 0);
        unsigned long long m2 = __ballot(base[128 + lane] > 0);
        unsigned long long m3 = __ballot(base[192 + lane] > 0);
        if (lane < 4) {
            unsigned long long v = lane == 0 ? m0 : lane == 1 ? m1 : lane == 2 ? m2 : m3;
            mask[wave * 4 + lane] = v;
        }
    }
}

// ---------------- K1: gemm -> swizzled WhT slab + fused s1/s2 epilogue ----------------
__global__ __launch_bounds__(256) void k_gemm(const float* __restrict__ x,
                                              const f16* __restrict__ WT,
                                              const float* __restrict__ a,
                                              f16* __restrict__ WhT,
                                              float* __restrict__ s1,
                                              float* __restrict__ s2) {
    __shared__ __align__(16) char gsmem[46080];
    int t = threadIdx.x;
    f16* Ah = (f16*)gsmem;               // [64][72]
    f16* Bt = (f16*)(gsmem + 9216);      // [256][72]
    int m0 = blockIdx.x * 64;
    int lane = t & 63, w = t >> 6;
    int lr = lane & 15, lg = lane >> 4;
    f32x4 acc[4][4] = {};

    for (int k0 = 0; k0 < FIN; k0 += 64) {
        {
            int r = t >> 2, c = (t & 3) * 16;
            const float* src = x + (size_t)(m0 + r) * FIN + k0 + c;
            f32x4 v0 = *(const f32x4*)(src);
            f32x4 v1 = *(const f32x4*)(src + 4);
            f32x4 v2 = *(const f32x4*)(src + 8);
            f32x4 v3 = *(const f32x4*)(src + 12);
            half8 h0, h1;
#pragma unroll
            for (int q = 0; q < 4; q++) {
                h0[q] = (f16)v0[q]; h0[q + 4] = (f16)v1[q];
                h1[q] = (f16)v2[q]; h1[q + 4] = (f16)v3[q];
            }
            f16* dst = Ah + r * 72 + c;
            *(half8*)dst = h0;
            *(half8*)(dst + 8) = h1;
        }
        {
            const f16* src = WT + (size_t)t * FIN + k0;
            f16* dst = Bt + t * 72;
#pragma unroll
            for (int q = 0; q < 8; q++)
                *(half8*)(dst + q * 8) = *(const half8*)(src + q * 8);
        }
        __syncthreads();
#pragma unroll
        for (int kc = 0; kc < 2; kc++) {
            int krow = kc * 32 + lg * 8;
            half8 af[4], bf[4];
#pragma unroll
            for (int fi = 0; fi < 4; fi++)
                af[fi] = *(half8*)(Ah + (fi * 16 + lr) * 72 + krow);
#pragma unroll
            for (int fo = 0; fo < 4; fo++)
                bf[fo] = *(half8*)(Bt + (w * 64 + fo * 16 + lr) * 72 + krow);
#pragma unroll
            for (int fi = 0; fi < 4; fi++)
#pragma unroll
                for (int fo = 0; fo < 4; fo++)
                    acc[fi][fo] = __builtin_amdgcn_mfma_f32_16x16x32_f16(
                        af[fi], bf[fo], acc[fi][fo], 0, 0, 0);
        }
        __syncthreads();
    }

    int b = m0 >> 11;
    int slab_i = (m0 & (NTOK - 1)) >> 6;
    int nbase = m0 & (NTOK - 1);

    // s1/s2 partials from fp32 acc (o-range fully inside block)
    float* sred = (float*)gsmem;          // [2][4][64] floats (aliases Ah)
    f16* slab = (f16*)(gsmem + 9216);     // 32 KB slab image (aliases Bt)
    float a1v[4], a2v[4];
#pragma unroll
    for (int fo = 0; fo < 4; fo++) {
        int o = w * 64 + fo * 16 + lr;
        a1v[fo] = a[o];
        a2v[fo] = a[FOUT + o];
    }
#pragma unroll
    for (int fi = 0; fi < 4; fi++) {
        f32x4 p1 = {}, p2 = {};
#pragma unroll
        for (int fo = 0; fo < 4; fo++) {
            p1 += acc[fi][fo] * a1v[fo];
            p2 += acc[fi][fo] * a2v[fo];
        }
#pragma unroll
        for (int q = 0; q < 4; q++) {
#pragma unroll
            for (int d = 1; d < 16; d <<= 1) {
                p1[q] += __shfl_xor(p1[q], d);
                p2[q] += __shfl_xor(p2[q], d);
            }
        }
        if (lr == 0) {
            int row = fi * 16 + lg * 4;
#pragma unroll
            for (int q = 0; q < 4; q++) {
                sred[w * 64 + row + q] = p1[q];
                sred[256 + w * 64 + row + q] = p2[q];
            }
        }
    }
    // swizzled f16 slab image into LDS
#pragma unroll
    for (int fi = 0; fi < 4; fi++) {
        int jg8 = fi * 2 + (lg >> 1), jq0 = (lg & 1) * 4;
#pragma unroll
        for (int fo = 0; fo < 4; fo++) {
            int o = w * 64 + fo * 16 + lr;
            half4 hv;
#pragma unroll
            for (int q = 0; q < 4; q++) hv[q] = (f16)acc[fi][fo][q];
            *(half4*)(slab + o * 64 + ((jg8 ^ (o & 7)) * 8) + jq0) = hv;
        }
    }
    __syncthreads();

    if (t < 64) {
        s1[(size_t)b * NTOK + nbase + t] =
            sred[t] + sred[64 + t] + sred[128 + t] + sred[192 + t];
    } else if (t < 128) {
        int r2 = t - 64;
        s2[(size_t)b * NTOK + nbase + r2] =
            sred[256 + r2] + sred[320 + r2] + sred[384 + r2] + sred[448 + r2];
    }
    // coalesced slab copy-out (layout identical to LDS image)
    {
        const int4* sl = (const int4*)slab;
        int4* gd = (int4*)(WhT + ((size_t)(b * 32 + slab_i) * 256) * 64);
#pragma unroll
        for (int i = 0; i < 8; i++) gd[i * 256 + t] = sl[i * 256 + t];
    }
}

// ---------------- K2b: mrow[b][i] = lrelu(s1[b][i] + max_j s2[b][j]) ----------------
__global__ __launch_bounds__(256) void k_rowmax(const float* __restrict__ s1,
                                                const float* __restrict__ s2,
                                                float* __restrict__ mrow) {
    __shared__ float red[4];
    int b = blockIdx.x, t = threadIdx.x;
    const float* s2b = s2 + (size_t)b * NTOK;
    float mx = -3.0e38f;
#pragma unroll
    for (int i = 0; i < 8; i++) mx = fmaxf(mx, s2b[t + i * 256]);
#pragma unroll
    for (int d = 1; d < 64; d <<= 1) mx = fmaxf(mx, __shfl_xor(mx, d));
    if ((t & 63) == 0) red[t >> 6] = mx;
    __syncthreads();
    float s2m = fmaxf(fmaxf(red[0], red[1]), fmaxf(red[2], red[3]));
#pragma unroll
    for (int i = 0; i < 8; i++) {
        int n = t + i * 256;
        float s = s1[(size_t)b * NTOK + n] + s2m;
        mrow[(size_t)b * NTOK + n] = fmaxf(s, ALPHA * s);
    }
}

// ---------------- K3: fused softmax(fixed shift) + P@Wh + ELU ----------------
// (R10/R11-validated structure)
__global__ __launch_bounds__(512, 2) void k_attn(const unsigned* __restrict__ mask32,
                                                 const f16* __restrict__ WhT,
                                                 const float* __restrict__ s1g,
                                                 const float* __restrict__ s2g,
                                                 const float* __restrict__ mg,
                                                 float* __restrict__ out) {
    __shared__ __align__(16) char smem[65536 + 8192 + 512];
    f16* Bl = (f16*)smem;                          // [2][16384] f16 (2x32KB)
    float* s2_lds = (float*)(smem + 65536);        // [2048]
    float* lpart = (float*)(smem + 65536 + 8192);  // [2][64]

    int b = blockIdx.x & 7;                        // batch -> XCD pinning
    int i0 = (blockIdx.x >> 3) * 64;
    int t = threadIdx.x;
    int lane = t & 63, w = t >> 6;
    int js = w & 1, oh = (w >> 1) & 1, rg = w >> 2;
    int lr = lane & 15, lg = lane >> 4;

    ((f32x4*)s2_lds)[t] = ((const f32x4*)(s2g + (size_t)b * NTOK))[t];

    const char* wsrc = (const char*)WhT + (size_t)b * (32 * 32768);
    {
        const char* src = wsrc + (w * 4) * 1024 + lane * 16;
        char* dst = (char*)Bl + (w * 4) * 1024;
#pragma unroll
        for (int k = 0; k < 4; k++) gload16(src + k * 1024, dst + k * 1024);
    }

    int r0 = i0 + rg * 32 + lr, r1 = r0 + 16;
    float s1r0 = s1g[(size_t)b * NTOK + r0];
    float s1r1 = s1g[(size_t)b * NTOK + r1];
    float mx0 = mg[(size_t)b * NTOK + r0];
    float mx1 = mg[(size_t)b * NTOK + r1];
    const unsigned* mr0 = mask32 + (size_t)(b * NTOK + r0) * 64 + js;
    const unsigned* mr1 = mask32 + (size_t)(b * NTOK + r1) * 64 + js;

    f32x4 acc0[8] = {}, acc1[8] = {};
    float l0 = 0.f, l1 = 0.f;
    int rswz = ((js * 4 + lg) ^ (lr & 7)) * 8;

    unsigned bw0 = mr0[0], bw1 = mr1[0];

    __syncthreads();                                // s2 + slab0 staged

    for (int s = 0; s < 32; s++) {
        int buf = s & 1;
        if (s < 31) {
            const char* src = wsrc + (size_t)(s + 1) * 32768 + (w * 4) * 1024 + lane * 16;
            char* dst = (char*)Bl + (buf ^ 1) * 32768 + (w * 4) * 1024;
#pragma unroll
            for (int k = 0; k < 4; k++) gload16(src + k * 1024, dst + k * 1024);
        }

        unsigned cw0 = bw0, cw1 = bw1;
        if (s < 31) { bw0 = mr0[(s + 1) * 2]; bw1 = mr1[(s + 1) * 2]; }
        unsigned bits0 = (cw0 >> (lg * 8)) & 0xffu;
        unsigned bits1 = (cw1 >> (lg * 8)) & 0xffu;

        int sb = s * 64 + js * 32 + lg * 8;
        f32x4 sA = *(const f32x4*)&s2_lds[sb];
        f32x4 sB = *(const f32x4*)&s2_lds[sb + 4];

        half8 ph0, ph1;
#pragma unroll
        for (int q = 0; q < 8; q++) {
            float sv = q < 4 ? sA[q & 3] : sB[q & 3];
            float sx = s1r0 + sv;
            float ev = fmaxf(sx, ALPHA * sx);
            float p = ((bits0 >> q) & 1) ? __expf(ev - mx0) : 0.f;
            l0 += p; ph0[q] = (f16)p;
            float sy = s1r1 + sv;
            float eu = fmaxf(sy, ALPHA * sy);
            float u = ((bits1 >> q) & 1) ? __expf(eu - mx1) : 0.f;
            l1 += u; ph1[q] = (f16)u;
        }

        const f16* bbase = Bl + buf * 16384 + (oh * 128 + lr) * 64 + rswz;
#pragma unroll
        for (int ot = 0; ot < 8; ot++) {
            half8 bf = *(const half8*)(bbase + ot * (16 * 64));
            acc0[ot] = __builtin_amdgcn_mfma_f32_16x16x32_f16(ph0, bf, acc0[ot], 0, 0, 0);
            acc1[ot] = __builtin_amdgcn_mfma_f32_16x16x32_f16(ph1, bf, acc1[ot], 0, 0, 0);
        }
        __syncthreads();
    }

    l0 += __shfl_xor(l0, 16); l0 += __shfl_xor(l0, 32);
    l1 += __shfl_xor(l1, 16); l1 += __shfl_xor(l1, 32);
    if (oh == 0 && lg == 0) {
        lpart[js * 64 + rg * 32 + lr] = l0;
        lpart[js * 64 + rg * 32 + 16 + lr] = l1;
    }
    __syncthreads();

    float* accx = (float*)smem;                     // [64][260]
    if (js == 1) {
#pragma unroll
        for (int ot = 0; ot < 8; ot++)
#pragma unroll
            for (int q = 0; q < 4; q++) {
                accx[(rg * 32 + lg * 4 + q) * 260 + oh * 128 + ot * 16 + lr] = acc0[ot][q];
                accx[(rg * 32 + 16 + lg * 4 + q) * 260 + oh * 128 + ot * 16 + lr] = acc1[ot][q];
            }
    }
    __syncthreads();
    if (js == 0) {
        f32x4 rl0, rl1;
#pragma unroll
        for (int q = 0; q < 4; q++) {
            int ra = rg * 32 + lg * 4 + q, rb = ra + 16;
            rl0[q] = 1.f / (lpart[ra] + lpart[64 + ra]);
            rl1[q] = 1.f / (lpart[rb] + lpart[64 + rb]);
        }
#pragma unroll
        for (int ot = 0; ot < 8; ot++) {
            int o = oh * 128 + ot * 16 + lr;
#pragma unroll
            for (int q = 0; q < 4; q++) {
                int ra = rg * 32 + lg * 4 + q;
                float u = (acc0[ot][q] + accx[ra * 260 + o]) * rl0[q];
                u = u > 0.f ? u : __expf(u) - 1.f;
                __builtin_nontemporal_store(u, &out[((size_t)(b * NTOK + i0 + ra)) * FOUT + o]);
                int rb = ra + 16;
                float v = (acc1[ot][q] + accx[rb * 260 + o]) * rl1[q];
                v = v > 0.f ? v : __expf(v) - 1.f;
                __builtin_nontemporal_store(v, &out[((size_t)(b * NTOK + i0 + rb)) * FOUT + o]);
            }
        }
    }
}

extern "C" void kernel_launch(void* const* d_in, const int* in_sizes, int n_in,
                              void* d_out, int out_size, void* d_ws, size_t ws_size,
                              hipStream_t stream) {
    const float* x = (const float*)d_in[0];
    const int* adj = (const int*)d_in[1];
    const float* W = (const float*)d_in[2];
    const float* a = (const float*)d_in[3];
    float* out = (float*)d_out;

    char* ws = (char*)d_ws;
    f16* WT = (f16*)ws;                                     // 128 KB
    f16* WhT = (f16*)(ws + 131072);                         // 8 MB swizzled
    float* s1 = (float*)(ws + 131072 + 8388608);            // 64 KB
    float* s2 = s1 + BATCH * NTOK;                          // 64 KB
    float* mrow = s2 + BATCH * NTOK;                        // 64 KB
    unsigned long long* mask64 =
        (unsigned long long*)(ws + 131072 + 8388608 + 196608);  // 4 MB

    k_pack<<<dim3(4096), 256, 0, stream>>>(adj, mask64);
    k_wt<<<dim3(FOUT / 32, FIN / 32), dim3(32, 32), 0, stream>>>(W, WT);
    k_gemm<<<dim3(BATCH * NTOK / 64), 256, 0, stream>>>(x, WT, a, WhT, s1, s2);
    k_rowmax<<<dim3(BATCH), 256, 0, stream>>>(s1, s2, mrow);
    k_attn<<<dim3(BATCH * NTOK / 64), 512, 0, stream>>>((const unsigned*)mask64, WhT,
                                                        s1, s2, mrow, out);
}

// Round 13
// 81.501 us; speedup vs baseline: 1.6890x; 1.0980x over previous
//
#include <hip/hip_runtime.h>
#include <hip/hip_fp16.h>

typedef _Float16 f16;
typedef _Float16 half4 __attribute__((ext_vector_type(4)));
typedef _Float16 half8 __attribute__((ext_vector_type(8)));
typedef float f32x4 __attribute__((ext_vector_type(4)));

#define BATCH 8
#define NTOK 2048
#define FIN 256
#define FOUT 256
#define ALPHA 0.2f

// WhT swizzled layout: [b][slab(32)][o(256)][u(8)][q(8)] f16; logical
// Wh[n][o] (n = slab*64 + jg8*8 + jq) lives at u = jg8 ^ (o & 7).
// Each slab is a contiguous 32 KB block == its LDS image in k_attn.

__device__ __forceinline__ void gload16(const void* g, void* l) {
    __builtin_amdgcn_global_load_lds(
        (const __attribute__((address_space(1))) unsigned int*)(g),
        (__attribute__((address_space(3))) unsigned int*)(l), 16, 0, 0);
}

// ---------------- K0: W[k][o] fp32 -> WT[o][k] fp16 ----------------
__global__ void k_wt(const float* __restrict__ W, f16* __restrict__ WT) {
    __shared__ float t[32][33];
    int o0 = blockIdx.x * 32, k0 = blockIdx.y * 32;
    int tx = threadIdx.x, ty = threadIdx.y;
    t[ty][tx] = W[(k0 + ty) * FOUT + o0 + tx];
    __syncthreads();
    WT[(o0 + ty) * FIN + (k0 + tx)] = (f16)t[tx][ty];
}

// ---------------- K1: gemm -> swizzled WhT slab + fused s1/s2 epilogue ----------------
__global__ __launch_bounds__(256) void k_gemm(const float* __restrict__ x,
                                              const f16* __restrict__ WT,
                                              const float* __restrict__ a,
                                              f16* __restrict__ WhT,
                                              float* __restrict__ s1,
                                              float* __restrict__ s2) {
    __shared__ __align__(16) char gsmem[46080];
    int t = threadIdx.x;
    f16* Ah = (f16*)gsmem;               // [64][72]
    f16* Bt = (f16*)(gsmem + 9216);      // [256][72]
    int m0 = blockIdx.x * 64;
    int lane = t & 63, w = t >> 6;
    int lr = lane & 15, lg = lane >> 4;
    f32x4 acc[4][4] = {};

    for (int k0 = 0; k0 < FIN; k0 += 64) {
        {
            int r = t >> 2, c = (t & 3) * 16;
            const float* src = x + (size_t)(m0 + r) * FIN + k0 + c;
            f32x4 v0 = *(const f32x4*)(src);
            f32x4 v1 = *(const f32x4*)(src + 4);
            f32x4 v2 = *(const f32x4*)(src + 8);
            f32x4 v3 = *(const f32x4*)(src + 12);
            half8 h0, h1;
#pragma unroll
            for (int q = 0; q < 4; q++) {
                h0[q] = (f16)v0[q]; h0[q + 4] = (f16)v1[q];
                h1[q] = (f16)v2[q]; h1[q + 4] = (f16)v3[q];
            }
            f16* dst = Ah + r * 72 + c;
            *(half8*)dst = h0;
            *(half8*)(dst + 8) = h1;
        }
        {
            const f16* src = WT + (size_t)t * FIN + k0;
            f16* dst = Bt + t * 72;
#pragma unroll
            for (int q = 0; q < 8; q++)
                *(half8*)(dst + q * 8) = *(const half8*)(src + q * 8);
        }
        __syncthreads();
#pragma unroll
        for (int kc = 0; kc < 2; kc++) {
            int krow = kc * 32 + lg * 8;
            half8 af[4], bf[4];
#pragma unroll
            for (int fi = 0; fi < 4; fi++)
                af[fi] = *(half8*)(Ah + (fi * 16 + lr) * 72 + krow);
#pragma unroll
            for (int fo = 0; fo < 4; fo++)
                bf[fo] = *(half8*)(Bt + (w * 64 + fo * 16 + lr) * 72 + krow);
#pragma unroll
            for (int fi = 0; fi < 4; fi++)
#pragma unroll
                for (int fo = 0; fo < 4; fo++)
                    acc[fi][fo] = __builtin_amdgcn_mfma_f32_16x16x32_f16(
                        af[fi], bf[fo], acc[fi][fo], 0, 0, 0);
        }
        __syncthreads();
    }

    int b = m0 >> 11;
    int slab_i = (m0 & (NTOK - 1)) >> 6;
    int nbase = m0 & (NTOK - 1);

    float* sred = (float*)gsmem;          // [2][4][64] floats (aliases Ah)
    f16* slab = (f16*)(gsmem + 9216);     // 32 KB slab image (aliases Bt)
    float a1v[4], a2v[4];
#pragma unroll
    for (int fo = 0; fo < 4; fo++) {
        int o = w * 64 + fo * 16 + lr;
        a1v[fo] = a[o];
        a2v[fo] = a[FOUT + o];
    }
#pragma unroll
    for (int fi = 0; fi < 4; fi++) {
        f32x4 p1 = {}, p2 = {};
#pragma unroll
        for (int fo = 0; fo < 4; fo++) {
            p1 += acc[fi][fo] * a1v[fo];
            p2 += acc[fi][fo] * a2v[fo];
        }
#pragma unroll
        for (int q = 0; q < 4; q++) {
#pragma unroll
            for (int d = 1; d < 16; d <<= 1) {
                p1[q] += __shfl_xor(p1[q], d);
                p2[q] += __shfl_xor(p2[q], d);
            }
        }
        if (lr == 0) {
            int row = fi * 16 + lg * 4;
#pragma unroll
            for (int q = 0; q < 4; q++) {
                sred[w * 64 + row + q] = p1[q];
                sred[256 + w * 64 + row + q] = p2[q];
            }
        }
    }
#pragma unroll
    for (int fi = 0; fi < 4; fi++) {
        int jg8 = fi * 2 + (lg >> 1), jq0 = (lg & 1) * 4;
#pragma unroll
        for (int fo = 0; fo < 4; fo++) {
            int o = w * 64 + fo * 16 + lr;
            half4 hv;
#pragma unroll
            for (int q = 0; q < 4; q++) hv[q] = (f16)acc[fi][fo][q];
            *(half4*)(slab + o * 64 + ((jg8 ^ (o & 7)) * 8) + jq0) = hv;
        }
    }
    __syncthreads();

    if (t < 64) {
        s1[(size_t)b * NTOK + nbase + t] =
            sred[t] + sred[64 + t] + sred[128 + t] + sred[192 + t];
    } else if (t < 128) {
        int r2 = t - 64;
        s2[(size_t)b * NTOK + nbase + r2] =
            sred[256 + r2] + sred[320 + r2] + sred[384 + r2] + sred[448 + r2];
    }
    {
        const int4* sl = (const int4*)slab;
        int4* gd = (int4*)(WhT + ((size_t)(b * 32 + slab_i) * 256) * 64);
#pragma unroll
        for (int i = 0; i < 8; i++) gd[i * 256 + t] = sl[i * 256 + t];
    }
}

// ---------------- K2b: mrow[b][i] = lrelu(s1[b][i] + max_j s2[b][j]) ----------------
__global__ __launch_bounds__(256) void k_rowmax(const float* __restrict__ s1,
                                                const float* __restrict__ s2,
                                                float* __restrict__ mrow) {
    __shared__ float red[4];
    int b = blockIdx.x, t = threadIdx.x;
    const float* s2b = s2 + (size_t)b * NTOK;
    float mx = -3.0e38f;
#pragma unroll
    for (int i = 0; i < 8; i++) mx = fmaxf(mx, s2b[t + i * 256]);
#pragma unroll
    for (int d = 1; d < 64; d <<= 1) mx = fmaxf(mx, __shfl_xor(mx, d));
    if ((t & 63) == 0) red[t >> 6] = mx;
    __syncthreads();
    float s2m = fmaxf(fmaxf(red[0], red[1]), fmaxf(red[2], red[3]));
#pragma unroll
    for (int i = 0; i < 8; i++) {
        int n = t + i * 256;
        float s = s1[(size_t)b * NTOK + n] + s2m;
        mrow[(size_t)b * NTOK + n] = fmaxf(s, ALPHA * s);
    }
}

// ---------------- K3: fused adj-stream + softmax(fixed shift) + P@Wh + ELU ----------------
// R10/R12-validated structure + adj DMA-staged into LDS (pack kernel deleted).
// Per 64-j step: WhT slab (32 KB) + adj tile (64 rows x 64 j, 16 KB) both
// double-buffered via global_load_lds (zero VGPR staging). 1 block/CU.
// adj LDS layout: [jchunk(8)][row(64)] of 32 B (8 ints) — 4-way conflict only.
__global__ __launch_bounds__(512, 1) void k_attn(const int* __restrict__ adj,
                                                 const f16* __restrict__ WhT,
                                                 const float* __restrict__ s1g,
                                                 const float* __restrict__ s2g,
                                                 const float* __restrict__ mg,
                                                 float* __restrict__ out) {
    __shared__ __align__(16) char smem[65536 + 32768 + 8192 + 512];
    f16* Bl = (f16*)smem;                           // 2 x 32 KB WhT slabs
    char* adjL = smem + 65536;                      // 2 x 16 KB adj tiles
    float* s2_lds = (float*)(smem + 98304);         // 8 KB
    float* lpart = (float*)(smem + 106496);         // [2][64]

    int b = blockIdx.x & 7;                         // batch -> XCD pinning
    int i0 = (blockIdx.x >> 3) * 64;
    int t = threadIdx.x;
    int lane = t & 63, w = t >> 6;
    int js = w & 1, oh = (w >> 1) & 1, rg = w >> 2;
    int lr = lane & 15, lg = lane >> 4;

    ((f32x4*)s2_lds)[t] = ((const f32x4*)(s2g + (size_t)b * NTOK))[t];

    const char* wsrc = (const char*)WhT + (size_t)b * (32 * 32768);
    const char* asrc0 = (const char*)adj +
        ((size_t)(b * NTOK + i0 + (lane >> 1))) * 8192 + w * 32 + (lane & 1) * 16;

    // prologue: stage slab 0 + adj tile 0 into buf 0
    {
        const char* src = wsrc + (w * 4) * 1024 + lane * 16;
        char* dst = (char*)Bl + (w * 4) * 1024;
#pragma unroll
        for (int k = 0; k < 4; k++) gload16(src + k * 1024, dst + k * 1024);
        char* adst = adjL + w * 2048;
#pragma unroll
        for (int k = 0; k < 2; k++)
            gload16(asrc0 + (size_t)k * 32 * 8192, adst + k * 1024);
    }

    int r0 = i0 + rg * 32 + lr, r1 = r0 + 16;
    float s1r0 = s1g[(size_t)b * NTOK + r0];
    float s1r1 = s1g[(size_t)b * NTOK + r1];
    float mx0 = mg[(size_t)b * NTOK + r0];
    float mx1 = mg[(size_t)b * NTOK + r1];

    f32x4 acc0[8] = {}, acc1[8] = {};
    float l0 = 0.f, l1 = 0.f;
    int rswz = ((js * 4 + lg) ^ (lr & 7)) * 8;      // WhT deswizzle
    int achunk = (js * 4 + lg) * 2048;              // adj chunk base
    int ar0 = (rg * 32 + lr) * 32, ar1 = ar0 + 512; // +16 rows * 32 B

    __syncthreads();                                 // s2 + slab0 + adj0 staged

    for (int s = 0; s < 32; s++) {
        int buf = s & 1;
        if (s < 31) {                                // stage next slab + adj tile
            const char* src = wsrc + (size_t)(s + 1) * 32768 + (w * 4) * 1024 + lane * 16;
            char* dst = (char*)Bl + (buf ^ 1) * 32768 + (w * 4) * 1024;
#pragma unroll
            for (int k = 0; k < 4; k++) gload16(src + k * 1024, dst + k * 1024);
            const char* asrc = asrc0 + (s + 1) * 256;
            char* adst = adjL + (buf ^ 1) * 16384 + w * 2048;
#pragma unroll
            for (int k = 0; k < 2; k++)
                gload16(asrc + (size_t)k * 32 * 8192, adst + k * 1024);
        }

        const char* ac = adjL + buf * 16384 + achunk;
        int4 a0 = *(const int4*)(ac + ar0);
        int4 a0b = *(const int4*)(ac + ar0 + 16);
        int4 a1 = *(const int4*)(ac + ar1);
        int4 a1b = *(const int4*)(ac + ar1 + 16);
        int av0[8] = {a0.x, a0.y, a0.z, a0.w, a0b.x, a0b.y, a0b.z, a0b.w};
        int av1[8] = {a1.x, a1.y, a1.z, a1.w, a1b.x, a1b.y, a1b.z, a1b.w};

        int sb = s * 64 + js * 32 + lg * 8;
        f32x4 sA = *(const f32x4*)&s2_lds[sb];
        f32x4 sB = *(const f32x4*)&s2_lds[sb + 4];

        half8 ph0, ph1;
#pragma unroll
        for (int q = 0; q < 8; q++) {
            float sv = q < 4 ? sA[q & 3] : sB[q & 3];
            float sx = s1r0 + sv;
            float ev = fmaxf(sx, ALPHA * sx);
            float p = (av0[q] > 0) ? __expf(ev - mx0) : 0.f;
            l0 += p; ph0[q] = (f16)p;
            float sy = s1r1 + sv;
            float eu = fmaxf(sy, ALPHA * sy);
            float u = (av1[q] > 0) ? __expf(eu - mx1) : 0.f;
            l1 += u; ph1[q] = (f16)u;
        }

        const f16* bbase = Bl + buf * 16384 + (oh * 128 + lr) * 64 + rswz;
#pragma unroll
        for (int ot = 0; ot < 8; ot++) {
            half8 bf = *(const half8*)(bbase + ot * (16 * 64));
            acc0[ot] = __builtin_amdgcn_mfma_f32_16x16x32_f16(ph0, bf, acc0[ot], 0, 0, 0);
            acc1[ot] = __builtin_amdgcn_mfma_f32_16x16x32_f16(ph1, bf, acc1[ot], 0, 0, 0);
        }
        __syncthreads();
    }

    l0 += __shfl_xor(l0, 16); l0 += __shfl_xor(l0, 32);
    l1 += __shfl_xor(l1, 16); l1 += __shfl_xor(l1, 32);
    if (oh == 0 && lg == 0) {
        lpart[js * 64 + rg * 32 + lr] = l0;
        lpart[js * 64 + rg * 32 + 16 + lr] = l1;
    }
    __syncthreads();

    float* accx = (float*)smem;                      // [64][260]
    if (js == 1) {
#pragma unroll
        for (int ot = 0; ot < 8; ot++)
#pragma unroll
            for (int q = 0; q < 4; q++) {
                accx[(rg * 32 + lg * 4 + q) * 260 + oh * 128 + ot * 16 + lr] = acc0[ot][q];
                accx[(rg * 32 + 16 + lg * 4 + q) * 260 + oh * 128 + ot * 16 + lr] = acc1[ot][q];
            }
    }
    __syncthreads();
    if (js == 0) {
        f32x4 rl0, rl1;
#pragma unroll
        for (int q = 0; q < 4; q++) {
            int ra = rg * 32 + lg * 4 + q, rb = ra + 16;
            rl0[q] = 1.f / (lpart[ra] + lpart[64 + ra]);
            rl1[q] = 1.f / (lpart[rb] + lpart[64 + rb]);
        }
#pragma unroll
        for (int ot = 0; ot < 8; ot++) {
            int o = oh * 128 + ot * 16 + lr;
#pragma unroll
            for (int q = 0; q < 4; q++) {
                int ra = rg * 32 + lg * 4 + q;
                float u = (acc0[ot][q] + accx[ra * 260 + o]) * rl0[q];
                u = u > 0.f ? u : __expf(u) - 1.f;
                __builtin_nontemporal_store(u, &out[((size_t)(b * NTOK + i0 + ra)) * FOUT + o]);
                int rb = ra + 16;
                float v = (acc1[ot][q] + accx[rb * 260 + o]) * rl1[q];
                v = v > 0.f ? v : __expf(v) - 1.f;
                __builtin_nontemporal_store(v, &out[((size_t)(b * NTOK + i0 + rb)) * FOUT + o]);
            }
        }
    }
}

extern "C" void kernel_launch(void* const* d_in, const int* in_sizes, int n_in,
                              void* d_out, int out_size, void* d_ws, size_t ws_size,
                              hipStream_t stream) {
    const float* x = (const float*)d_in[0];
    const int* adj = (const int*)d_in[1];
    const float* W = (const float*)d_in[2];
    const float* a = (const float*)d_in[3];
    float* out = (float*)d_out;

    char* ws = (char*)d_ws;
    f16* WT = (f16*)ws;                                     // 128 KB
    f16* WhT = (f16*)(ws + 131072);                         // 8 MB swizzled
    float* s1 = (float*)(ws + 131072 + 8388608);            // 64 KB
    float* s2 = s1 + BATCH * NTOK;                          // 64 KB
    float* mrow = s2 + BATCH * NTOK;                        // 64 KB

    k_wt<<<dim3(FOUT / 32, FIN / 32), dim3(32, 32), 0, stream>>>(W, WT);
    k_gemm<<<dim3(BATCH * NTOK / 64), 256, 0, stream>>>(x, WT, a, WhT, s1, s2);
    k_rowmax<<<dim3(BATCH), 256, 0, stream>>>(s1, s2, mrow);
    k_attn<<<dim3(BATCH * NTOK / 64), 512, 0, stream>>>(adj, WhT, s1, s2, mrow, out);
}